// Round 13
// baseline (268.752 us; speedup 1.0000x reference)
//
#include <hip/hip_runtime.h>
#include <hip/hip_bf16.h>

#define BB 16
#define DDIM 256
#define TLEN 4096
#define KCODES 1024
#define NQ (BB*TLEN)   // 65536
#define QB 64          // queries per k_mdist block
#define MAXC 32

#define FLT_MAX_C 3.402823466e+38f

using short8 = __attribute__((ext_vector_type(8))) short;
using f32x4  = __attribute__((ext_vector_type(4))) float;

// RNE fp32 -> bf16 (bit pattern)
__device__ __forceinline__ unsigned short f2bf(float x) {
  unsigned u = __float_as_uint(x);
  unsigned r = (u + 0x7fffu + ((u >> 16) & 1u)) >> 16;
  return (unsigned short)r;
}

// ---------------------------------------------------------------------------
// numpy pairwise 8-accumulator block over 128 elements (half of n=256).
// np_sumsq_256(x) == fadd(block(x), block(x+128)) exactly.
// ---------------------------------------------------------------------------
__device__ __forceinline__ float np_sumsq_128(const float* q, int stride) {
  float r[8];
#pragma unroll
  for (int j = 0; j < 8; ++j) {
    float v = q[(size_t)j * (size_t)stride];
    r[j] = __fmul_rn(v, v);
  }
  for (int i = 8; i < 128; i += 8) {
#pragma unroll
    for (int j = 0; j < 8; ++j) {
      float v = q[(size_t)(i + j) * (size_t)stride];
      r[j] = __fadd_rn(r[j], __fmul_rn(v, v));
    }
  }
  return __fadd_rn(__fadd_rn(__fadd_rn(r[0], r[1]), __fadd_rn(r[2], r[3])),
                   __fadd_rn(__fadd_rn(r[4], r[5]), __fadd_rn(r[6], r[7])));
}
__device__ __forceinline__ float np_sumsq_256s(const float* p, int stride) {
  return __fadd_rn(np_sumsq_128(p, stride),
                   np_sumsq_128(p + (size_t)128 * stride, stride));
}

// ---------------------------------------------------------------------------
// k_prep: embT (for gather), e2 exact, bf16-hi of emb, maxe = max|e|
// ---------------------------------------------------------------------------
__global__ void k_prep(const float* __restrict__ emb, float* __restrict__ embT,
                       float* __restrict__ e2, short* __restrict__ ebh,
                       unsigned* __restrict__ maxe) {
  const int k = blockIdx.x;
  const int d = threadIdx.x;
  __shared__ float row[DDIM];
  float v = emb[(size_t)k * DDIM + d];
  row[d] = v;
  embT[(size_t)d * KCODES + k] = v;
  ebh[(size_t)k * DDIM + d] = (short)f2bf(v);
  float a = fabsf(v);
#pragma unroll
  for (int m = 1; m < 64; m <<= 1) a = fmaxf(a, __shfl_xor(a, m, 64));
  if ((threadIdx.x & 63) == 0) atomicMax(maxe, __float_as_uint(a));
  __syncthreads();
  if (d == 0) e2[k] = np_sumsq_256s(row, 1);
}

// ---------------------------------------------------------------------------
// k_mdist v9: 512 threads = 8 waves; block = 64 queries x 1024 codes.
// LDS 65KB -> 2 blocks/CU, 4 waves/SIMD (vs r12's 1 block / 2 waves):
//   zs 32KB  - z staged in two d-halves (A-build + z2/sabs per half);
//              becomes epilogue scratch after A-build.
//   abh 32KB - A-fragments [8ks][4mt][64lane].
//   tail 1KB - z2s, sabs, cnt, ovf (persist).
// MFMA: two code-halves (kb = ch*512 + w*64), acc[4][4] f32x4 = 64 VGPR,
// 4-deep rotating B prefetch; live ~111 <= 128 cap (r12-proven shape).
// Filter: one MFMA pass; per-half window 0.016*maxe*sabs_q + 2e-4
// (superset of global window -> rigorous). Exact fp32 recheck of
// candidates (reference rounding chain, z from global; block's z tile is
// L2-hot) -> bit-exact first-occurrence argmin. Outputs idx/oidx/hist/lossp.
// ---------------------------------------------------------------------------
__global__ __launch_bounds__(512, 1)
void k_mdist(const float* __restrict__ z, const float* __restrict__ emb,
             const short* __restrict__ ebh, const float* __restrict__ e2,
             const unsigned* __restrict__ maxeU, int* __restrict__ idx,
             float* __restrict__ oidx, int* __restrict__ hist,
             double* __restrict__ lossp) {
  extern __shared__ __align__(16) char sbuf[];        // 66560 bytes
  float*  zs   = (float*)sbuf;                        // [128][64] staging
  // epilogue aliases of zs (valid after A-build):
  float* sm    = (float*)sbuf;                        // [8][64]   2KB
  float* qmin  = (float*)(sbuf + 2048);               // [64]
  int*   cand  = (int*)(sbuf + 4096);                 // [64][MAXC] 8KB
  float* bd    = (float*)(sbuf + 12288);              // [64][8]   2KB
  int*   bk    = (int*)(sbuf + 14336);                // [64][8]   2KB
  short8* abh  = (short8*)(sbuf + 32768);             // [8ks][4mt][64lane] 32KB
  // persistent tail:
  float* z2s   = (float*)(sbuf + 65536);              // [64]
  float* sabs  = (float*)(sbuf + 65536 + 256);        // [64]
  int*   cnt   = (int*)(sbuf + 65536 + 512);          // [64]
  int*   ovf   = (int*)(sbuf + 65536 + 768);          // [64]

  const int tid = threadIdx.x;
  const int lane = tid & 63;
  const int w = tid >> 6;    // 0..7
  const int g = lane >> 4;   // 0..3
  const int c = lane & 15;
  const int n0 = blockIdx.x * QB;
  const int b = n0 >> 12;
  const int t0 = n0 & (TLEN - 1);
  const float* zp = z + (size_t)b * DDIM * TLEN + t0;

  // ---- 1. two d-halves: stage zs + A-build + z2/sabs partials ----
  float th0 = 0.f, sa0 = 0.f;
#pragma unroll
  for (int h = 0; h < 2; ++h) {
#pragma unroll
    for (int i = 0; i < 4; ++i) {
      int s4 = i * 512 + tid;          // 2048 float4 slots
      int dl = s4 >> 4, q4 = (s4 & 15) * 4;
      *(float4*)&zs[dl * QB + q4] =
          *(const float4*)(zp + (size_t)(h * 128 + dl) * TLEN + q4);
    }
    __syncthreads();
#pragma unroll
    for (int i = 0; i < 2; ++i) {
      int s = i * 512 + tid;           // 1024 slots: ks_l(4) x mt(4) x lane(64)
      int ksl = s >> 8, mt = (s >> 6) & 3, ln = s & 63;
      int q = mt * 16 + (ln & 15);
      int d0l = ksl * 32 + (ln >> 4) * 8;
      short8 hh;
#pragma unroll
      for (int j = 0; j < 8; ++j) hh[j] = (short)f2bf(zs[(d0l + j) * QB + q]);
      abh[(h * 4 + ksl) * 256 + mt * 64 + ln] = hh;
    }
    if (tid < QB) {
      float th = np_sumsq_128(&zs[tid], QB);
      float sa = 0.f;
      for (int d = 0; d < 128; ++d) sa += fabsf(zs[d * QB + tid]);
      if (h == 0) {
        th0 = th; sa0 = sa;
        cnt[tid] = 0; ovf[tid] = 0;
      } else {
        z2s[tid] = __fadd_rn(th0, th);
        sabs[tid] = sa0 + sa;
      }
    }
    __syncthreads();
  }

  const float maxe = __uint_as_float(*maxeU);

  // ---- 2. two code-halves: MFMA (64q x 512c) + per-half filter ----
#pragma unroll 1
  for (int ch = 0; ch < 2; ++ch) {
    const int kb = ch * 512 + w * 64;

    f32x4 acc[4][4];
#pragma unroll
    for (int mt = 0; mt < 4; ++mt)
#pragma unroll
      for (int nt = 0; nt < 4; ++nt) {
        f32x4 zz = {0.f, 0.f, 0.f, 0.f};
        acc[mt][nt] = zz;
      }

    const short* ebp = ebh + (size_t)(kb + c) * DDIM + g * 8;
    short8 bbuf[4];
#pragma unroll
    for (int nt = 0; nt < 4; ++nt)
      bbuf[nt] = *(const short8*)(ebp + nt * (16 * DDIM));

    for (int ks = 0; ks < 8; ++ks) {
      short8 ah[4];
#pragma unroll
      for (int mt = 0; mt < 4; ++mt) ah[mt] = abh[ks * 256 + mt * 64 + lane];
      const int ksn = (ks + 1) & 7;
#pragma unroll
      for (int nt = 0; nt < 4; ++nt) {
        short8 bv = bbuf[nt];
        bbuf[nt] = *(const short8*)(ebp + nt * (16 * DDIM) + ksn * 32);
#pragma unroll
        for (int mt = 0; mt < 4; ++mt)
          acc[mt][nt] = __builtin_amdgcn_mfma_f32_16x16x32_bf16(
              ah[mt], bv, acc[mt][nt], 0, 0, 0);
      }
    }

    float e2c[4];
#pragma unroll
    for (int nt = 0; nt < 4; ++nt) e2c[nt] = e2[kb + nt * 16 + c];

#pragma unroll
    for (int mt = 0; mt < 4; ++mt) {
      float m4[4];
#pragma unroll
      for (int r = 0; r < 4; ++r) {
        float m = FLT_MAX_C;
#pragma unroll
        for (int nt = 0; nt < 4; ++nt)
          m = fminf(m, e2c[nt] - 2.0f * acc[mt][nt][r]);
#pragma unroll
        for (int s = 1; s < 16; s <<= 1) m = fminf(m, __shfl_xor(m, s, 64));
        m4[r] = m;
      }
      if (c == 0) {
#pragma unroll
        for (int r = 0; r < 4; ++r) sm[w * 64 + mt * 16 + g * 4 + r] = m4[r];
      }
    }
    __syncthreads();
    if (tid < QB) {
      float m = sm[tid];
#pragma unroll
      for (int wv = 1; wv < 8; ++wv) m = fminf(m, sm[wv * 64 + tid]);
      qmin[tid] = m;
    }
    __syncthreads();

#pragma unroll
    for (int mt = 0; mt < 4; ++mt)
#pragma unroll
      for (int r = 0; r < 4; ++r) {
        const int ql = mt * 16 + g * 4 + r;
        const float lim = qmin[ql] + (maxe * sabs[ql]) * 0.016f + 2e-4f;
#pragma unroll
        for (int nt = 0; nt < 4; ++nt) {
          float s = e2c[nt] - 2.0f * acc[mt][nt][r];
          if (s <= lim) {
            int p = atomicAdd(&cnt[ql], 1);
            if (p < MAXC) cand[ql * MAXC + p] = kb + nt * 16 + c;
            else ovf[ql] = 1;
          }
        }
      }
    __syncthreads();
  }

  // ---- 3. exact recheck (reference fp32 chain; z from global), 8 slots/q ----
  {
    const int q = tid & 63;
    const int slot = tid >> 6;
    const float z2q = z2s[q];
    const float* zq = zp + q;   // stride TLEN over d (block's tile is L2-hot)
    float bestd = FLT_MAX_C;
    int besti = (1 << 30);
    const bool all = (ovf[q] != 0) || (cnt[q] > MAXC);
    const int count = all ? KCODES : cnt[q];
    for (int ci = slot; ci < count; ci += 8) {
      const int k = all ? ci : cand[q * MAXC + ci];
      const float* ek = emb + (size_t)k * DDIM;
      float a0 = 0.f;
      for (int d = 0; d < DDIM; ++d)
        a0 = __fmaf_rn(zq[(size_t)d * TLEN], ek[d], a0);
      float dist = __fsub_rn(__fadd_rn(z2q, e2[k]), __fmul_rn(2.0f, a0));
      if (dist < bestd || (dist == bestd && k < besti)) { bestd = dist; besti = k; }
    }
    bd[q * 8 + slot] = bestd;
    bk[q * 8 + slot] = besti;
  }
  __syncthreads();

  // ---- 4. final per-query reduce; idx/oidx/hist/loss outputs ----
  if (tid < QB) {
    float B = bd[tid * 8 + 0];
    int K = bk[tid * 8 + 0];
#pragma unroll
    for (int s = 1; s < 8; ++s) {
      float d2 = bd[tid * 8 + s];
      int k2 = bk[tid * 8 + s];
      if (d2 < B || (d2 == B && k2 < K)) { B = d2; K = k2; }
    }
    K &= (KCODES - 1);
    idx[n0 + tid] = K;
    oidx[n0 + tid] = (float)K;
    atomicAdd(&hist[K], 1);
    double ls = (double)B;
#pragma unroll
    for (int m = 1; m < 64; m <<= 1) ls += __shfl_xor(ls, m, 64);
    if (tid == 0) lossp[blockIdx.x] = ls;
  }
}

// ---------------------------------------------------------------------------
// k_gather: out[b,d,t] = emb[idx[b,t], d]; one block per (b,d);
// embT row cached in LDS; int4 idx loads + float4 stores (coalesced).
// ---------------------------------------------------------------------------
__global__ void k_gather(const float* __restrict__ embT,
                         const int* __restrict__ idx,
                         float* __restrict__ out) {
  __shared__ float er[KCODES];
  const int blk = blockIdx.x;  // b*D + d
  const int bq = blk >> 8;
  const int d = blk & 255;
  const int tid = threadIdx.x;
  *((float4*)&er[tid * 4]) =
      *((const float4*)(embT + (size_t)d * KCODES + tid * 4));
  __syncthreads();
  const int* ip = idx + (size_t)bq * TLEN;
  float* op = out + (size_t)blk * TLEN;
#pragma unroll
  for (int cch = 0; cch < 4; ++cch) {
    int t0 = cch * 1024 + tid * 4;
    int4 ii = *(const int4*)&ip[t0];
    float4 v;
    v.x = er[ii.x & (KCODES - 1)];
    v.y = er[ii.y & (KCODES - 1)];
    v.z = er[ii.z & (KCODES - 1)];
    v.w = er[ii.w & (KCODES - 1)];
    *(float4*)&op[t0] = v;
  }
}

// ---------------------------------------------------------------------------
// k_final: loss and perplexity (deterministic fixed-tree reductions)
// ---------------------------------------------------------------------------
__global__ void k_final(const int* __restrict__ hist,
                        const double* __restrict__ lossp,
                        float* __restrict__ out2) {
  const int tid = threadIdx.x;  // 256
  double ls = 0.0;
  for (int i = 0; i < 4; ++i) ls += lossp[tid * 4 + i];  // 1024 partials
  float es = 0.f;
  for (int i = tid; i < KCODES; i += 256) {
    float p = (float)hist[i] / 65536.0f;
    es += p * logf(p + 1e-10f);
  }
#pragma unroll
  for (int m = 1; m < 64; m <<= 1) {
    ls += __shfl_xor(ls, m, 64);
    es += __shfl_xor(es, m, 64);
  }
  __shared__ double lw[4];
  __shared__ float ew[4];
  if ((tid & 63) == 0) { lw[tid >> 6] = ls; ew[tid >> 6] = es; }
  __syncthreads();
  if (tid == 0) {
    double lt = lw[0] + lw[1] + lw[2] + lw[3];
    float et = ew[0] + ew[1] + ew[2] + ew[3];
    float loss = 0.25f * (float)(lt / (double)((long long)NQ * DDIM));
    float perp = expf(-et);
    out2[0] = loss;
    out2[1] = perp;
  }
}

// ---------------------------------------------------------------------------
// workspace layout (bytes):
//   embT  : 0        .. 1048576   (D*K floats)
//   e2    : 1048576  .. 1052672   (K floats)
//   hist  : 1052672  .. 1056768   (K ints)     <- memset each launch (+maxe)
//   maxe  : 1056768  .. 1056772   (1 uint)
//   lossp : 1056776  .. 1064968   (1024 doubles, fully written)
//   idx   : 1064968  .. 1327112   (N ints)
//   ebh   : 1327112  .. 1851400   (K*D bf16 hi)
// total ~1.85 MB
// ---------------------------------------------------------------------------
extern "C" void kernel_launch(void* const* d_in, const int* in_sizes, int n_in,
                              void* d_out, int out_size, void* d_ws, size_t ws_size,
                              hipStream_t stream) {
  const float* z = (const float*)d_in[0];
  const float* emb = (const float*)d_in[1];
  float* out = (float*)d_out;

  char* ws = (char*)d_ws;
  float* embT = (float*)(ws);
  float* e2 = (float*)(ws + 1048576);
  int* hist = (int*)(ws + 1052672);
  unsigned* maxe = (unsigned*)(ws + 1056768);
  double* lossp = (double*)(ws + 1056776);
  int* idx = (int*)(ws + 1064968);
  short* ebh = (short*)(ws + 1327112);

  float* oidx = out + ((size_t)out_size - 2 - NQ);
  float* out2 = out + ((size_t)out_size - 2);

  // dynamic LDS for k_mdist: 66560 bytes -> 2 blocks/CU
  (void)hipFuncSetAttribute((const void*)k_mdist,
                            hipFuncAttributeMaxDynamicSharedMemorySize,
                            66560);

  hipMemsetAsync(hist, 0, 4100, stream);  // hist + maxe

  k_prep<<<KCODES, 256, 0, stream>>>(emb, embT, e2, ebh, maxe);
  k_mdist<<<NQ / QB, 512, 66560, stream>>>(z, emb, ebh, e2, maxe, idx, oidx,
                                           hist, lossp);
  k_gather<<<BB * DDIM, 256, 0, stream>>>(embT, idx, out);
  k_final<<<1, 256, 0, stream>>>(hist, lossp, out2);
}